// Round 1
// baseline (244.220 us; speedup 1.0000x reference)
//
#include <hip/hip_runtime.h>
#include <hip/hip_bf16.h>
#include <math.h>

// ---------------------------------------------------------------------------
// HierarchicalVAE fused pipeline for MI355X (gfx950), fp32 end-to-end.
// B=128, P=2 paths, SEG=4 cubic segments, T=8 samples/seg, canvas 28, AA=2.
//
// Output layout (flat f32, return-order concat):
//   rendered [128,1,28,28] @ 0        (100352)
//   mu       [128,64]      @ 100352   (8192)
//   logvar   [128,64]      @ 108544   (8192)
//   cp       [128,2,4,4,2] @ 116736   (8192)
//   widths   [128,2]       @ 124928   (256)
//   alphas   [128,2]       @ 125184   (256)
// ---------------------------------------------------------------------------

#define O_IMG 0
#define O_MU  100352
#define O_LV  108544
#define O_CP  116736
#define O_WD  124928
#define O_AL  125184

#define BATCH 128

// activation: 0=none 1=leaky_relu(0.2) 2=selu 3=tanh
template<int ACT>
__device__ __forceinline__ float act_fn(float x) {
    if (ACT == 1) return x >= 0.0f ? x : 0.2f * x;
    if (ACT == 2) {
        const float scale = 1.0507009873554805f;
        const float alpha = 1.6732632423543772f;
        return x > 0.0f ? scale * x : scale * (alpha * expm1f(x));
    }
    if (ACT == 3) return tanhf(x);
    return x;
}

// C[128,N] = act(A[128,lda(K)] @ W[K,N] + b)
// grid (N/64, 128/4), block 256 = 4 rows x 64 cols
template<int K, int N, int ACT>
__global__ __launch_bounds__(256)
void gemm_act(const float* __restrict__ A, int lda,
              const float* __restrict__ W, const float* __restrict__ bias,
              float* __restrict__ out) {
    __shared__ float sA[4][K];
    const int j0 = blockIdx.x * 64;
    const int r0 = blockIdx.y * 4;
    for (int idx = threadIdx.x; idx < 4 * K; idx += 256) {
        int r = idx / K;
        int k = idx - r * K;
        sA[r][k] = A[(r0 + r) * lda + k];
    }
    __syncthreads();
    const int r = threadIdx.x >> 6;
    const int j = j0 + (threadIdx.x & 63);
    float acc0 = bias[j], acc1 = 0.f, acc2 = 0.f, acc3 = 0.f;
    const float* __restrict__ a = &sA[r][0];
    for (int k = 0; k < K; k += 4) {
        acc0 = fmaf(a[k + 0], W[(k + 0) * N + j], acc0);
        acc1 = fmaf(a[k + 1], W[(k + 1) * N + j], acc1);
        acc2 = fmaf(a[k + 2], W[(k + 2) * N + j], acc2);
        acc3 = fmaf(a[k + 3], W[(k + 3) * N + j], acc3);
    }
    float acc = (acc0 + acc1) + (acc2 + acc3);
    out[(r0 + r) * N + j] = act_fn<ACT>(acc);
}

// mu, logvar, z. grid 64, block 256 (2 rows/block, 128 outputs/row)
__global__ __launch_bounds__(256)
void k_muvz(const float* __restrict__ h,
            const float* __restrict__ mu_w, const float* __restrict__ mu_b,
            const float* __restrict__ lv_w, const float* __restrict__ lv_b,
            const float* __restrict__ eps,
            float* __restrict__ out, float* __restrict__ hin) {
    __shared__ float sA[2][256];
    __shared__ float sO[2][128];
    const int r0 = blockIdx.x * 2;
    for (int idx = threadIdx.x; idx < 512; idx += 256)
        sA[idx >> 8][idx & 255] = h[(r0 + (idx >> 8)) * 256 + (idx & 255)];
    __syncthreads();
    {
        const int r = threadIdx.x >> 7;
        const int o = threadIdx.x & 127;
        const int j = o & 63;
        const bool is_lv = o >= 64;
        const float* __restrict__ W = is_lv ? lv_w : mu_w;
        float acc = is_lv ? lv_b[j] : mu_b[j];
        const float* __restrict__ a = &sA[r][0];
        for (int k = 0; k < 256; k += 4) {
            acc = fmaf(a[k + 0], W[(k + 0) * 64 + j], acc);
            acc = fmaf(a[k + 1], W[(k + 1) * 64 + j], acc);
            acc = fmaf(a[k + 2], W[(k + 2) * 64 + j], acc);
            acc = fmaf(a[k + 3], W[(k + 3) * 64 + j], acc);
        }
        sO[r][o] = acc;
        out[(is_lv ? O_LV : O_MU) + (r0 + r) * 64 + j] = acc;
    }
    __syncthreads();
    if (threadIdx.x < 128) {
        const int r = threadIdx.x >> 6;
        const int j = threadIdx.x & 63;
        float mu = sO[r][j];
        float lv = sO[r][64 + j];
        float z = fmaf(eps[(r0 + r) * 64 + j], expf(0.5f * lv), mu);
        hin[(r0 + r) * 92 + j] = z;   // h_in[0:64] = z
    }
}

// cp head (tanh -> pts_norm into h_in[64:92]), widths, alphas.
// grid 128 (1 row/block), block 256: 32 outputs x 8 lanes each
__global__ __launch_bounds__(256)
void k_heads(const float* __restrict__ h2,
             const float* __restrict__ cp_w, const float* __restrict__ cp_b,
             const float* __restrict__ wd_w, const float* __restrict__ wd_b,
             const float* __restrict__ al_w, const float* __restrict__ al_b,
             float* __restrict__ out, float* __restrict__ hin) {
    __shared__ float sH[512];
    const int row = blockIdx.x;
    for (int i = threadIdx.x; i < 512; i += 256) sH[i] = h2[row * 512 + i];
    __syncthreads();
    const int o = threadIdx.x >> 3;
    const int g = threadIdx.x & 7;
    const float* __restrict__ W;
    int ldw, col;
    if (o < 28)      { W = cp_w; ldw = 28; col = o; }
    else if (o < 30) { W = wd_w; ldw = 2;  col = o - 28; }
    else             { W = al_w; ldw = 2;  col = o - 30; }
    float acc = 0.f;
    for (int k = g; k < 512; k += 8) acc = fmaf(sH[k], W[k * ldw + col], acc);
    acc += __shfl_xor(acc, 1);
    acc += __shfl_xor(acc, 2);
    acc += __shfl_xor(acc, 4);
    if (g == 0) {
        if (o < 28) {
            hin[row * 92 + 64 + o] = tanhf(acc + cp_b[col]);  // pts_norm
        } else if (o < 30) {
            float v = 1.f / (1.f + expf(-(acc + wd_b[col])));
            out[O_WD + row * 2 + col] = fmaf(v, 2.f, 1.f);
        } else {
            float v = 1.f / (1.f + expf(-(acc + al_b[col])));
            out[O_AL + row * 2 + col] = v;
        }
    }
}

// refined = tanh(r1 @ ref_w2 + b) -> points -> control_points (out) + q (ws)
// grid 128, block 256: 64 outputs x 4 lanes
__global__ __launch_bounds__(256)
void k_final(const float* __restrict__ r1,
             const float* __restrict__ w2, const float* __restrict__ b2,
             float* __restrict__ out, float* __restrict__ q) {
    __shared__ float sR[512];
    __shared__ float sP[52];   // points, [p*26 + i*2 + d]
    const int row = blockIdx.x;
    for (int i = threadIdx.x; i < 512; i += 256) sR[i] = r1[row * 512 + i];
    __syncthreads();
    const int o = threadIdx.x >> 2;
    const int g = threadIdx.x & 3;
    float acc = 0.f;
    if (o < 52)
        for (int k = g; k < 512; k += 4) acc = fmaf(sR[k], w2[k * 52 + o], acc);
    acc += __shfl_xor(acc, 1);
    acc += __shfl_xor(acc, 2);
    if (g == 0 && o < 52)
        sP[o] = fmaf(tanhf(acc + b2[o]), 12.f, 14.f);  // *SCALE + HALF
    __syncthreads();
    if (threadIdx.x < 64) {
        // control_points[p][s][k][d] = points[p][3s+k][d]
        int idx = threadIdx.x;
        int p = idx >> 5, rest = idx & 31;
        int s = rest >> 3, kk = (rest >> 1) & 3, d = idx & 1;
        out[O_CP + row * 64 + idx] = sP[p * 26 + (3 * s + kk) * 2 + d];
    }
    if (threadIdx.x < 128) {
        // q[p][s*8+t][d] = sum_k basis[t][k] * cp[p][s][k][d]
        int idx = threadIdx.x;
        int p = idx >> 6, s = (idx >> 4) & 3, ti = (idx >> 1) & 7, d = idx & 1;
        float t = (float)ti / 7.0f;
        float mt = 1.0f - t;
        float c0 = mt * mt * mt;
        float c1 = 3.f * mt * mt * t;
        float c2 = 3.f * mt * t * t;
        float c3 = t * t * t;
        const float* base = &sP[p * 26 + (3 * s) * 2 + d];
        float v = c0 * base[0] + c1 * base[2] + c2 * base[4] + c3 * base[6];
        q[row * 128 + idx] = v;  // idx == p*64 + m*2 + d
    }
}

// Rasterizer. grid (7, 128), block 448 = 112 pixels x 4 AA subsamples.
__global__ __launch_bounds__(448)
void k_raster(const float* __restrict__ q, const float* __restrict__ wa,
              float* __restrict__ out) {
    __shared__ float2 sQ[2][32];
    __shared__ float sWA[4];   // w0 w1 a0 a1
    const int b = blockIdx.y;
    const int chunk = blockIdx.x;
    if (threadIdx.x < 128)
        ((float*)sQ)[threadIdx.x] = q[b * 128 + threadIdx.x];
    if (threadIdx.x < 4) {
        int t = threadIdx.x;
        sWA[t] = (t < 2) ? wa[O_WD + b * 2 + t] : wa[O_AL + b * 2 + (t - 2)];
    }
    __syncthreads();
    const int pixel = chunk * 112 + (threadIdx.x >> 2);
    const int sub = threadIdx.x & 3;
    const int py = pixel / 28;
    const int px = pixel - py * 28;
    const float sy = ((float)(2 * py + (sub >> 1)) + 0.5f) * 0.5f;
    const float sx = ((float)(2 * px + (sub & 1)) + 0.5f) * 0.5f;
    float img = 1.0f;
#pragma unroll
    for (int p = 0; p < 2; p++) {
        float dmin2 = 1e30f;
        int cnt = 0;
        float2 cur = sQ[p][0];
        bool bp = cur.y > sy;
#pragma unroll
        for (int m = 0; m < 32; m++) {
            float2 nxt = sQ[p][(m + 1) & 31];
            float dx = sx - cur.x;
            float dy = sy - cur.y;
            dmin2 = fminf(dmin2, fmaf(dx, dx, dy * dy));
            bool bn = nxt.y > sy;
            // sx < x0 + ((sy-y0)/(y1-y0+1e-8))*(x1-x0), division-free:
            float den = nxt.y - cur.y + 1e-8f;
            float lhs = (sx - cur.x) * den;
            float rhs = (sy - cur.y) * (nxt.x - cur.x);
            if ((bp != bn) && ((lhs < rhs) == (den > 0.0f))) cnt++;
            cur = nxt;
            bp = bn;
        }
        float dist = sqrtf(dmin2);
        float stroke = fminf(fmaxf(fmaf(sWA[p], 0.5f, 0.5f) - dist, 0.f), 1.f);
        float cov = fmaxf((float)(cnt & 1), stroke);
        img *= fmaf(-sWA[2 + p], cov, 1.0f);
    }
    img += __shfl_xor(img, 1);
    img += __shfl_xor(img, 2);
    if (sub == 0) out[O_IMG + b * 784 + pixel] = 1.0f - 0.25f * img;
}

extern "C" void kernel_launch(void* const* d_in, const int* in_sizes, int n_in,
                              void* d_out, int out_size, void* d_ws, size_t ws_size,
                              hipStream_t stream) {
    const float* x      = (const float*)d_in[0];
    const float* eps    = (const float*)d_in[1];
    const float* enc_w1 = (const float*)d_in[2];
    const float* enc_b1 = (const float*)d_in[3];
    const float* enc_w2 = (const float*)d_in[4];
    const float* enc_b2 = (const float*)d_in[5];
    const float* mu_w   = (const float*)d_in[6];
    const float* mu_b   = (const float*)d_in[7];
    const float* lv_w   = (const float*)d_in[8];
    const float* lv_b   = (const float*)d_in[9];
    const float* dec_w1 = (const float*)d_in[10];
    const float* dec_b1 = (const float*)d_in[11];
    const float* dec_w2 = (const float*)d_in[12];
    const float* dec_b2 = (const float*)d_in[13];
    const float* cp_w   = (const float*)d_in[14];
    const float* cp_b   = (const float*)d_in[15];
    const float* ref_w1 = (const float*)d_in[16];
    const float* ref_b1 = (const float*)d_in[17];
    const float* ref_w2 = (const float*)d_in[18];
    const float* ref_b2 = (const float*)d_in[19];
    const float* wd_w   = (const float*)d_in[20];
    const float* wd_b   = (const float*)d_in[21];
    const float* al_w   = (const float*)d_in[22];
    const float* al_b   = (const float*)d_in[23];

    float* out = (float*)d_out;
    float* ws  = (float*)d_ws;

    float* h1  = ws;             // 128*256
    float* h   = ws + 32768;     // 128*256
    float* hin = ws + 65536;     // 128*92  (z | pts_norm)
    float* d1  = ws + 77312;     // 128*512
    float* h2  = ws + 142848;    // 128*512
    float* r1  = ws + 208384;    // 128*512
    float* qb  = ws + 273920;    // 128*128

    gemm_act<784, 256, 1><<<dim3(4, 32), 256, 0, stream>>>(x, 784, enc_w1, enc_b1, h1);
    gemm_act<256, 256, 1><<<dim3(4, 32), 256, 0, stream>>>(h1, 256, enc_w2, enc_b2, h);
    k_muvz<<<64, 256, 0, stream>>>(h, mu_w, mu_b, lv_w, lv_b, eps, out, hin);
    gemm_act<64, 512, 2><<<dim3(8, 32), 256, 0, stream>>>(hin, 92, dec_w1, dec_b1, d1);
    gemm_act<512, 512, 2><<<dim3(8, 32), 256, 0, stream>>>(d1, 512, dec_w2, dec_b2, h2);
    k_heads<<<128, 256, 0, stream>>>(h2, cp_w, cp_b, wd_w, wd_b, al_w, al_b, out, hin);
    gemm_act<92, 512, 2><<<dim3(8, 32), 256, 0, stream>>>(hin, 92, ref_w1, ref_b1, r1);
    k_final<<<128, 256, 0, stream>>>(r1, ref_w2, ref_b2, out, qb);
    k_raster<<<dim3(7, 128), 448, 0, stream>>>(qb, out, out);
}